// Round 11
// baseline (1063.813 us; speedup 1.0000x reference)
//
#include <hip/hip_runtime.h>

#define N_NODES 50000
#define N_PAD   50048          // 391 * 128
#define N_EDGES 800000
#define N_REL   8
#define NSEG    (N_REL * N_NODES)      // 400000
#define SCAN_NB 391                    // ceil(NSEG / 1024)
#define NSTRIPE 391                    // 128-row stripes
#define SPX     49                     // ceil(391/8) stripes per XCD

typedef short bf16x8 __attribute__((ext_vector_type(8)));
typedef float f32x4  __attribute__((ext_vector_type(4)));

__device__ __forceinline__ ushort f2bf(float f) {
    union { float f; unsigned u; } c; c.f = f;
    unsigned u = c.u + 0x7fffu + ((c.u >> 16) & 1u);   // RNE
    return (ushort)(u >> 16);
}
__device__ __forceinline__ void add8(float* s, uint4 v) {
    unsigned u[4] = {v.x, v.y, v.z, v.w};
    #pragma unroll
    for (int k = 0; k < 4; ++k) {
        s[2 * k]     += __uint_as_float(u[k] << 16);
        s[2 * k + 1] += __uint_as_float(u[k] & 0xffff0000u);
    }
}

// ---------------- edge preprocessing: counting sort by (rel*N + dst) ----------------

__global__ void count_edges(const int* __restrict__ dst, const int* __restrict__ et,
                            int* __restrict__ cnt) {
    int e = blockIdx.x * 256 + threadIdx.x;
    if (e < N_EDGES) atomicAdd(&cnt[et[e] * N_NODES + dst[e]], 1);
}

__global__ __launch_bounds__(256) void scan_pass1(const int* __restrict__ cnt,
                                                  int* __restrict__ sums) {
    __shared__ int sc[256];
    int b = blockIdx.x, t = threadIdx.x;
    int base = b * 1024 + t * 4;
    int v = 0;
    #pragma unroll
    for (int i = 0; i < 4; ++i) { int idx = base + i; if (idx < NSEG) v += cnt[idx]; }
    sc[t] = v; __syncthreads();
    for (int off = 1; off < 256; off <<= 1) {
        int x = (t >= off) ? sc[t - off] : 0;
        __syncthreads(); sc[t] += x; __syncthreads();
    }
    if (t == 255) sums[b] = sc[255];
}

__global__ __launch_bounds__(512) void scan_pass2(int* __restrict__ sums, int nb) {
    __shared__ int sc[512];
    int t = threadIdx.x;
    int v = (t < nb) ? sums[t] : 0;
    sc[t] = v; __syncthreads();
    for (int off = 1; off < 512; off <<= 1) {
        int x = (t >= off) ? sc[t - off] : 0;
        __syncthreads(); sc[t] += x; __syncthreads();
    }
    if (t < nb) sums[t] = sc[t] - v;     // exclusive
}

__global__ __launch_bounds__(256) void scan_pass3(const int* __restrict__ cnt,
                                                  const int* __restrict__ sums,
                                                  int* __restrict__ row_ptr) {
    __shared__ int sc[256];
    int b = blockIdx.x, t = threadIdx.x;
    int base = b * 1024 + t * 4;
    int e[4]; int v = 0;
    #pragma unroll
    for (int i = 0; i < 4; ++i) { int idx = base + i; e[i] = (idx < NSEG) ? cnt[idx] : 0; v += e[i]; }
    sc[t] = v; __syncthreads();
    for (int off = 1; off < 256; off <<= 1) {
        int x = (t >= off) ? sc[t - off] : 0;
        __syncthreads(); sc[t] += x; __syncthreads();
    }
    int run = sums[b] + (sc[t] - v);
    #pragma unroll
    for (int i = 0; i < 4; ++i) {
        int idx = base + i;
        if (idx < NSEG) row_ptr[idx] = run;
        run += e[i];
    }
    if (b == 0 && t == 0) row_ptr[NSEG] = N_EDGES;
}

// cnt doubles as the placement cursor (atomicSub); cnt is dead afterwards.
__global__ void place_edges(const int* __restrict__ src, const int* __restrict__ dst,
                            const int* __restrict__ et, const int* __restrict__ row_ptr,
                            int* __restrict__ cnt, int* __restrict__ sorted_src) {
    int e = blockIdx.x * 256 + threadIdx.x;
    if (e >= N_EDGES) return;
    int key = et[e] * N_NODES + dst[e];
    int old = atomicSub(&cnt[key], 1);
    sorted_src[row_ptr[key] + old - 1] = src[e];
}

// ---------------- weight pack: BT[col][k] bf16, col = r*O+o (r=8 -> root), zero-pad cols ----------------

__global__ void convert_weights(const float* __restrict__ W, const float* __restrict__ root,
                                ushort* __restrict__ BT, int K, int O, int NPAD) {
    int idx = blockIdx.x * 256 + threadIdx.x;
    if (idx >= NPAD * K) return;
    int col = idx / K, i = idx % K;
    float v = 0.0f;
    if (col < N_REL * O) {
        int r = col / O, o = col % O;
        v = W[((size_t)r * K + i) * O + o];
    } else if (col < (N_REL + 1) * O) {
        v = root[(size_t)i * O + (col - N_REL * O)];
    }
    BT[idx] = f2bf(v);
}

__global__ void f32_to_bf16(const float* __restrict__ in, ushort* __restrict__ out, int n4) {
    int i = blockIdx.x * 256 + threadIdx.x;
    if (i >= n4) return;
    float4 v = ((const float4*)in)[i];
    ushort4 s; s.x = f2bf(v.x); s.y = f2bf(v.y); s.z = f2bf(v.z); s.w = f2bf(v.w);
    ((ushort4*)out)[i] = s;
}

// ---------------- barrier-free direct-load MFMA GEMM (XCD-pinned swizzle kept) ----------------
// After the XCD swizzle (round 10: FETCH 112->32 MB) A and B are L2-resident, so the
// m97 LDS staging (and its vmcnt(0)+barrier drain + 8-way b128 conflicts) is pure
// overhead. Each lane loads its MFMA fragments directly global->VGPR (16 rows x full
// 64B lines per instruction, coalesced), manually double-buffered so step s+1 loads
// fly under step s MFMAs (AITER-style partial vmcnt). No __syncthreads anywhere.
// Epilogue: wave-private LDS transpose -> full-line 128B stores.
template<int K, int CTS>
__global__ __launch_bounds__(256)
void gemm_direct(const ushort* __restrict__ A, const ushort* __restrict__ BT,
                 ushort* __restrict__ Y, int NW) {
    // ---- swizzle: f -> (stripe y, col-tile ct) pinned to XCD f&7 ----
    const int f = blockIdx.x;
    const int g = f & 7, m = f >> 3;
    const int y = g + 8 * (m / CTS);
    const int ct = m % CTS;
    if (y >= NSTRIPE) return;
    const int row0 = y * 128;
    const int col0 = ct * 128;

    __shared__ ushort TsAll[4 * 32 * 72];       // epilogue transpose scratch only
    const int t = threadIdx.x;
    const int lane = t & 63;
    const int w = t >> 6;
    const int l16 = lane & 15, q = lane >> 4;
    const int wm = (w & 1) * 64, wn = (w >> 1) * 64;

    const ushort* Ap = A + (size_t)(row0 + wm + l16) * K + q * 8;
    const ushort* Bp = BT + (size_t)(col0 + wn + l16) * K + q * 8;

    constexpr int NS = K / 32;
    f32x4 acc[4][4] = {};

    bf16x8 a0[4], b0[4];
    #pragma unroll
    for (int i = 0; i < 4; ++i) {
        a0[i] = *(const bf16x8*)(Ap + (size_t)i * 16 * K);
        b0[i] = *(const bf16x8*)(Bp + (size_t)i * 16 * K);
    }
    #pragma unroll
    for (int s = 0; s < NS; ++s) {
        bf16x8 a1[4], b1[4];
        if (s + 1 < NS) {                        // prefetch next k-step (flies under MFMA)
            const int kn = (s + 1) * 32;
            #pragma unroll
            for (int i = 0; i < 4; ++i) {
                a1[i] = *(const bf16x8*)(Ap + (size_t)i * 16 * K + kn);
                b1[i] = *(const bf16x8*)(Bp + (size_t)i * 16 * K + kn);
            }
        }
        #pragma unroll
        for (int i = 0; i < 4; ++i)
            #pragma unroll
            for (int j = 0; j < 4; ++j)
                acc[i][j] = __builtin_amdgcn_mfma_f32_16x16x32_bf16(a0[i], b0[j], acc[i][j], 0, 0, 0);
        if (s + 1 < NS) {
            #pragma unroll
            for (int i = 0; i < 4; ++i) { a0[i] = a1[i]; b0[i] = b1[i]; }
        }
    }

    // ---- epilogue: two-pass transpose via wave-private LDS (32 rows x stride 72),
    // then full-line stores: 8 lanes cover 128 B of one row per instruction.
    ushort* Ts = &TsAll[w * 32 * 72];
    const int rr = lane >> 3;                    // 0..7 row within 8-row group
    const int cc = (lane & 7) * 8;               // 16B chunk within row
    #pragma unroll
    for (int half = 0; half < 2; ++half) {
        // scatter: D mapping col=l16, row=q*4+reg (verified gfx950 layout)
        #pragma unroll
        for (int i = 0; i < 2; ++i)
            #pragma unroll
            for (int j = 0; j < 4; ++j)
                #pragma unroll
                for (int r = 0; r < 4; ++r)
                    Ts[(i * 16 + q * 4 + r) * 72 + j * 16 + l16] = f2bf(acc[half * 2 + i][j][r]);
        // gather+store (wave-private region; compiler orders LDS ops via lgkmcnt)
        #pragma unroll
        for (int p = 0; p < 4; ++p) {
            int row = p * 8 + rr;                // 0..31 local
            uint4 v = *(const uint4*)&Ts[row * 72 + cc];
            *(uint4*)(Y + (size_t)(row0 + wm + half * 32 + row) * NW + col0 + wn + cc) = v;
        }
    }
}

// ---------------- fused gather: out[d] = act( root + bias + sum_r mean_r ) ----------------
// Thread owns (dst node, 8-col chunk); segment bounds preloaded for MLP; no atomics.
template<int O>
__global__ __launch_bounds__(256)
void gather_kernel(const ushort* __restrict__ Y, int NW,
                   const int* __restrict__ row_ptr, const int* __restrict__ sorted_src,
                   const float* __restrict__ bias,
                   float* __restrict__ out_f32, ushort* __restrict__ out_bf16, int relu) {
    constexpr int TPN = O / 8;
    int d = blockIdx.x * (256 / TPN) + threadIdx.x / TPN;
    if (d >= N_NODES) return;
    int c0 = (threadIdx.x % TPN) * 8;
    int s0[N_REL], s1[N_REL];
    #pragma unroll
    for (int r = 0; r < N_REL; ++r) {
        s0[r] = row_ptr[r * N_NODES + d];
        s1[r] = row_ptr[r * N_NODES + d + 1];
    }
    float sum[8] = {};
    add8(sum, *(const uint4*)(Y + (size_t)d * NW + N_REL * O + c0));   // root slice
    #pragma unroll
    for (int k = 0; k < 8; ++k) sum[k] += bias[c0 + k];
    for (int r = 0; r < N_REL; ++r) {
        if (s1[r] <= s0[r]) continue;
        float ps[8] = {};
        const ushort* Yc = Y + r * O + c0;
        for (int e = s0[r]; e < s1[r]; ++e)
            add8(ps, *(const uint4*)(Yc + (size_t)sorted_src[e] * NW));
        float inv = 1.0f / (float)(s1[r] - s0[r]);
        #pragma unroll
        for (int k = 0; k < 8; ++k) sum[k] += ps[k] * inv;
    }
    if (relu) {
        #pragma unroll
        for (int k = 0; k < 8; ++k) sum[k] = fmaxf(sum[k], 0.0f);
    }
    if (out_bf16) {
        ushort o[8];
        #pragma unroll
        for (int k = 0; k < 8; ++k) o[k] = f2bf(sum[k]);
        *(uint4*)(out_bf16 + (size_t)d * O + c0) = *(const uint4*)o;
    } else {
        float* p = out_f32 + (size_t)d * O + c0;
        *(float4*)p = make_float4(sum[0], sum[1], sum[2], sum[3]);
        *(float4*)(p + 4) = make_float4(sum[4], sum[5], sum[6], sum[7]);
    }
}

// ---------------- host side ----------------

extern "C" void kernel_launch(void* const* d_in, const int* in_sizes, int n_in,
                              void* d_out, int out_size, void* d_ws, size_t ws_size,
                              hipStream_t stream) {
    const float* x  = (const float*)d_in[0];
    const int*   ei = (const int*)d_in[1];
    const int*   et = (const int*)d_in[2];
    const float* W[4]  = {(const float*)d_in[3], (const float*)d_in[6], (const float*)d_in[9],  (const float*)d_in[12]};
    const float* RT[4] = {(const float*)d_in[4], (const float*)d_in[7], (const float*)d_in[10], (const float*)d_in[13]};
    const float* BI[4] = {(const float*)d_in[5], (const float*)d_in[8], (const float*)d_in[11], (const float*)d_in[14]};
    const int KS[4] = {128, 256, 256, 256};
    const int NP[4] = {2304, 2304, 2304, 640};   // packed+padded BT rows (= Y width)
    const int* src = ei;
    const int* dst = ei + N_EDGES;

    // ---- workspace carve-up (same footprint as proven round-3 plan A) ----
    char* ws = (char*)d_ws;
    size_t off = 0;
    auto take = [&](size_t bytes) -> char* {
        char* p = ws + off;
        off = (off + bytes + 255) & ~(size_t)255;
        return p;
    };
    int* cnt        = (int*)take((size_t)NSEG * 4);
    int* row_ptr    = (int*)take((size_t)(NSEG + 1) * 4);
    int* sums       = (int*)take(512 * 4);
    int* sorted_src = (int*)take((size_t)N_EDGES * 4);
    ushort* BTp[4];
    for (int l = 0; l < 4; ++l) BTp[l] = (ushort*)take((size_t)NP[l] * KS[l] * 2);
    ushort* hb = (ushort*)take((size_t)N_PAD * 256 * 2);
    ushort* Yb = (ushort*)take((size_t)N_PAD * 2304 * 2);

    // ---- edge preprocessing (once per call) ----
    hipMemsetAsync(cnt, 0, (size_t)NSEG * 4, stream);
    count_edges<<<(N_EDGES + 255) / 256, 256, 0, stream>>>(dst, et, cnt);
    scan_pass1<<<SCAN_NB, 256, 0, stream>>>(cnt, sums);
    scan_pass2<<<1, 512, 0, stream>>>(sums, SCAN_NB);
    scan_pass3<<<SCAN_NB, 256, 0, stream>>>(cnt, sums, row_ptr);
    place_edges<<<(N_EDGES + 255) / 256, 256, 0, stream>>>(src, dst, et, row_ptr, cnt, sorted_src);

    // ---- weight pack ----
    for (int l = 0; l < 4; ++l) {
        int n = NP[l] * KS[l];
        convert_weights<<<(n + 255) / 256, 256, 0, stream>>>(W[l], RT[l], BTp[l], KS[l],
                                                             l == 3 ? 64 : 256, NP[l]);
    }

    // ---- input to bf16 ----
    f32_to_bf16<<<(N_NODES * 128 / 4 + 255) / 256, 256, 0, stream>>>(x, hb, N_NODES * 128 / 4);

    // ---- 4 layers: XCD-swizzled direct-load GEMM + fused gather ----
    const int G18 = 8 * SPX * 18;   // 7056
    const int G5  = 8 * SPX * 5;    // 1960
    gemm_direct<128, 18><<<G18, 256, 0, stream>>>(hb, BTp[0], Yb, 2304);
    gather_kernel<256><<<dim3((N_NODES + 7) / 8), 256, 0, stream>>>(
        Yb, 2304, row_ptr, sorted_src, BI[0], nullptr, hb, 1);

    gemm_direct<256, 18><<<G18, 256, 0, stream>>>(hb, BTp[1], Yb, 2304);
    gather_kernel<256><<<dim3((N_NODES + 7) / 8), 256, 0, stream>>>(
        Yb, 2304, row_ptr, sorted_src, BI[1], nullptr, hb, 1);

    gemm_direct<256, 18><<<G18, 256, 0, stream>>>(hb, BTp[2], Yb, 2304);
    gather_kernel<256><<<dim3((N_NODES + 7) / 8), 256, 0, stream>>>(
        Yb, 2304, row_ptr, sorted_src, BI[2], nullptr, hb, 1);

    gemm_direct<256, 5><<<G5, 256, 0, stream>>>(hb, BTp[3], Yb, 640);
    gather_kernel<64><<<dim3((N_NODES + 31) / 32), 256, 0, stream>>>(
        Yb, 640, row_ptr, sorted_src, BI[3], (float*)d_out, nullptr, 0);
}